// Round 8
// baseline (523.937 us; speedup 1.0000x reference)
//
#include <hip/hip_runtime.h>

// GRU_10746008175428 round 8: r7 + split-accumulate done right.
// B=512 T=512 E=64 H=128 P=96.
// 64 blocks x 512 thr: blocks 0-31 layer0 (producer), 32-63 layer1 (consumer).
// Per step (per wave): ds_read h -> 12 hh-MFMA (critical chain FIRST) ->
// 12 x-MFMA for NEXT step's gate pre-activations (independent of h; issue
// overlaps the gate trans/VALU phase) -> gates -> ds_write -> lgkm barrier.
// vs r7: split-acc with hh-first ordering (r6 had Q before hh + in-loop cvt
// = its regression); publish drain merged into step barrier; s_sleep(2).
// Numerics identical to r7 (same MFMA ops, same C-init) -> absmax invariant.

#define B_SZ 512
#define T_SZ 512
#define E_SZ 64
#define H_SZ 128
#define P_SZ 96
#define NB   16
#define NGRP (B_SZ / NB)          // 32
#define SC_SIG  (-1.44269504f)   // -log2(e)
#define SC_TANH (-2.88539008f)   // -2*log2(e)

typedef _Float16 half8 __attribute__((ext_vector_type(8)));
typedef float    f32x4 __attribute__((ext_vector_type(4)));

__device__ __forceinline__ float exp2_(float x) {
#if __has_builtin(__builtin_amdgcn_exp2f)
    return __builtin_amdgcn_exp2f(x);
#else
    return exp2f(x);
#endif
}
__device__ __forceinline__ float rcp_(float x) {
#if __has_builtin(__builtin_amdgcn_rcpf)
    return __builtin_amdgcn_rcpf(x);
#else
    return 1.0f / x;
#endif
}

// XOR-swizzled byte offset in a [rows][256B] LDS tile
__device__ __forceinline__ int swz256(int row, int byte) {
    return row * 256 + (byte ^ ((row & 7) << 4));
}

// One B-fragment (16 cols x 32 k) from fp32 weight matrix W, pre-scaled.
__device__ __forceinline__ void load_bfrag(const float* __restrict__ W, int ldk,
                                           int n0, int kt, int ln, float scale,
                                           half8* hi) {
    int n = n0 + (ln & 15);
    int k = kt * 32 + (ln >> 4) * 8;
    const float* p = W + (size_t)n * ldk + k;
    float4 a = *(const float4*)p;
    float4 b = *(const float4*)(p + 4);
    float v[8] = {a.x, a.y, a.z, a.w, b.x, b.y, b.z, b.w};
    half8 h;
    #pragma unroll
    for (int j = 0; j < 8; ++j)
        h[j] = (_Float16)(v[j] * scale);
    *hi = h;
}

#define LOADX(Sx, tt)                                                              \
    if ((tt) < T_SZ) {                                                             \
        _Pragma("unroll") for (int kt = 0; kt < KFX; ++kt)                         \
            Sx[kt] = *(const half8*)(xlane + (size_t)(tt) * ROWB + kt * 64);       \
    }

// Xd: dead x-buffer (receives x(tcur+2)); Xl: live x-buffer (x(tcur+1), feeds
// next step's Q-accs). P*: this step's pre-activations (bias + x-part already
// accumulated last step; hh added here). Q*: next step's bias + x-part.
#define GRU_STEP(Xd, Xl, P_R, P_Z, P_N, Q_R, Q_Z, Q_N, tcur)                       \
    {                                                                              \
        const char* hb = hs[(tcur) & 1];                                           \
        half8 ah[4];                                                               \
        _Pragma("unroll") for (int kt = 0; kt < 4; ++kt)                           \
            ah[kt] = *(const half8*)(hb + swz256(colg, kt * 64 + rgrp * 16));      \
        f32x4 cNH = {bh2s, bh2s, bh2s, bh2s};                                      \
        __builtin_amdgcn_s_setprio(1);                                             \
        _Pragma("unroll") for (int kt = 0; kt < 4; ++kt) {                         \
            P_R = __builtin_amdgcn_mfma_f32_16x16x32_f16(ah[kt], bhh[0][kt], P_R, 0, 0, 0); \
            P_Z = __builtin_amdgcn_mfma_f32_16x16x32_f16(ah[kt], bhh[1][kt], P_Z, 0, 0, 0); \
            cNH = __builtin_amdgcn_mfma_f32_16x16x32_f16(ah[kt], bhh[2][kt], cNH, 0, 0, 0); \
        }                                                                          \
        Q_R = (f32x4){bs0, bs0, bs0, bs0};                                         \
        Q_Z = (f32x4){bs1, bs1, bs1, bs1};                                         \
        Q_N = (f32x4){bi2s, bi2s, bi2s, bi2s};                                     \
        _Pragma("unroll") for (int kt = 0; kt < KFX; ++kt) {                       \
            Q_R = __builtin_amdgcn_mfma_f32_16x16x32_f16(Xl[kt], bx[0][kt], Q_R, 0, 0, 0); \
            Q_Z = __builtin_amdgcn_mfma_f32_16x16x32_f16(Xl[kt], bx[1][kt], Q_Z, 0, 0, 0); \
            Q_N = __builtin_amdgcn_mfma_f32_16x16x32_f16(Xl[kt], bx[2][kt], Q_N, 0, 0, 0); \
        }                                                                          \
        LOADX(Xd, (tcur) + 2)                                                      \
        float hn_[4];                                                              \
        _Pragma("unroll") for (int j = 0; j < 4; ++j) {                            \
            float rr = rcp_(1.f + exp2_(P_R[j]));                                  \
            float zz = rcp_(1.f + exp2_(P_Z[j]));                                  \
            float v  = P_N[j] + rr * cNH[j];                                       \
            float nn = fmaf(2.f, rcp_(1.f + exp2_(v)), -1.f);                      \
            hn_[j] = nn + zz * (hreg[j] - nn);                                     \
            hreg[j] = hn_[j];                                                      \
        }                                                                          \
        __builtin_amdgcn_s_setprio(0);                                             \
        char* hw = hs[((tcur) + 1) & 1];                                           \
        _Pragma("unroll") for (int j = 0; j < 4; ++j) {                            \
            int bb = rgrp * 4 + j;                                                 \
            *(_Float16*)(hw + swz256(bb, cw * 2)) = (_Float16)hn_[j];              \
            if constexpr (OUT_ALL) {                                               \
                ((_Float16*)hout)[((size_t)(b0 + bb) * T_SZ + (tcur)) * H_SZ + cw] \
                    = (_Float16)hn_[j];                                            \
            } else {                                                               \
                if ((tcur) == T_SZ - 1)                                            \
                    ((float*)hout)[(size_t)(b0 + bb) * H_SZ + cw] = hn_[j];        \
            }                                                                      \
        }                                                                          \
        if (ROLE == 0 && (((tcur) & 7) == 7)) {                                    \
            /* publish step: drain stores within the step barrier, then release */ \
            asm volatile("s_waitcnt vmcnt(0) lgkmcnt(0)" ::: "memory");            \
            __builtin_amdgcn_s_barrier();                                          \
            if (tid == 0)                                                          \
                __hip_atomic_store(prog, (tcur) + 1, __ATOMIC_RELEASE,             \
                                   __HIP_MEMORY_SCOPE_AGENT);                      \
        } else {                                                                   \
            asm volatile("s_waitcnt lgkmcnt(0)" ::: "memory");                     \
            __builtin_amdgcn_s_barrier();                                          \
        }                                                                          \
        __builtin_amdgcn_sched_barrier(0);                                         \
    }

// ROLE 0 = producer (layer 0), ROLE 1 = consumer (layer 1)
template<int K_IN, bool OUT_ALL, int ROLE>
__device__ __forceinline__ void gru_body(const _Float16* __restrict__ xin,
                                         const float* __restrict__ W_ih,
                                         const float* __restrict__ W_hh,
                                         const float* __restrict__ b_ih,
                                         const float* __restrict__ b_hh,
                                         void* __restrict__ hout,
                                         int* __restrict__ prog,
                                         int grp, char (*hs)[4096])
{
    constexpr int KFX  = K_IN / 32;
    constexpr int ROWB = K_IN * 2;     // fp16 row bytes

    const int tid  = threadIdx.x;
    const int ln   = tid & 63;
    const int wv   = tid >> 6;        // wave 0..7 -> col tile
    const int colg = ln & 15;
    const int rgrp = ln >> 4;
    const int b0   = grp * NB;
    const int cw   = wv * 16 + colg;  // hidden-unit column 0..127

    // ---- resident weight fragments (pre-scaled per gate) ----
    half8 bx[3][KFX];        // W_ih fp16
    half8 bhh[3][4];         // W_hh fp16
    const float gsc[3] = {SC_SIG, SC_SIG, SC_TANH};
    #pragma unroll
    for (int g = 0; g < 3; ++g) {
        int n0 = g * 128 + wv * 16;
        #pragma unroll
        for (int kt = 0; kt < KFX; ++kt)
            load_bfrag(W_ih, K_IN, n0, kt, ln, gsc[g], &bx[g][kt]);
        #pragma unroll
        for (int kt = 0; kt < 4; ++kt)
            load_bfrag(W_hh, H_SZ, n0, kt, ln, gsc[g], &bhh[g][kt]);
    }
    const float bs0  = SC_SIG  * (b_ih[cw] + b_hh[cw]);
    const float bs1  = SC_SIG  * (b_ih[128 + cw] + b_hh[128 + cw]);
    const float bi2s = SC_TANH * b_ih[256 + cw];
    const float bh2s = SC_TANH * b_hh[256 + cw];

    if (tid < 256) *(float4*)(hs[0] + tid * 16) = make_float4(0.f, 0.f, 0.f, 0.f);
    float hreg[4] = {0.f, 0.f, 0.f, 0.f};

    // per-lane x row base: A-row = colg (batch), k-offset rgrp*8 elems (16B)
    const char* xlane = (const char*)xin
        + (size_t)(b0 + colg) * T_SZ * ROWB
        + rgrp * 16;

    int avail = 0;
    if (ROLE == 1) {
        while (avail < 4) {
            avail = __hip_atomic_load(prog, __ATOMIC_ACQUIRE, __HIP_MEMORY_SCOPE_AGENT);
            if (avail < 4) __builtin_amdgcn_s_sleep(2);
        }
    }

    half8 Xa[KFX], Xb[KFX];
    LOADX(Xa, 0)
    LOADX(Xb, 1)

    // prologue: P0 = bias + x(0)-part (from Xa)
    f32x4 P0R, P0Z, P0N, P1R, P1Z, P1N;
    P0R = (f32x4){bs0, bs0, bs0, bs0};
    P0Z = (f32x4){bs1, bs1, bs1, bs1};
    P0N = (f32x4){bi2s, bi2s, bi2s, bi2s};
    #pragma unroll
    for (int kt = 0; kt < KFX; ++kt) {
        P0R = __builtin_amdgcn_mfma_f32_16x16x32_f16(Xa[kt], bx[0][kt], P0R, 0, 0, 0);
        P0Z = __builtin_amdgcn_mfma_f32_16x16x32_f16(Xa[kt], bx[1][kt], P0Z, 0, 0, 0);
        P0N = __builtin_amdgcn_mfma_f32_16x16x32_f16(Xa[kt], bx[2][kt], P0N, 0, 0, 0);
    }
    __syncthreads();

    for (int t = 0; t < T_SZ; t += 2) {
        if (ROLE == 1 && avail < T_SZ) {
            const int need = (t + 4 < T_SZ) ? t + 4 : T_SZ;
            while (avail < need) {
                avail = __hip_atomic_load(prog, __ATOMIC_ACQUIRE, __HIP_MEMORY_SCOPE_AGENT);
                if (avail < need) __builtin_amdgcn_s_sleep(2);
            }
        }
        // step t:   consume P0 (has x(t)),   build P1 = bias + x(t+1) from Xb, load Xa <- x(t+2)
        // step t+1: consume P1,              build P0 = bias + x(t+2) from Xa, load Xb <- x(t+3)
        GRU_STEP(Xa, Xb, P0R, P0Z, P0N, P1R, P1Z, P1N, t)
        GRU_STEP(Xb, Xa, P1R, P1Z, P1N, P0R, P0Z, P0N, t + 1)
    }
}

__global__ __launch_bounds__(512)
void gru_fused(const _Float16* __restrict__ xh,  // (B,T,64) fp16
               _Float16* __restrict__ h1,        // (B,T,128) fp16
               float* __restrict__ h2,           // (B,128) f32
               const float* __restrict__ W_ih0, const float* __restrict__ W_hh0,
               const float* __restrict__ b_ih0, const float* __restrict__ b_hh0,
               const float* __restrict__ W_ih1, const float* __restrict__ W_hh1,
               const float* __restrict__ b_ih1, const float* __restrict__ b_hh1,
               int* __restrict__ prog)
{
    __shared__ __align__(16) char hs[2][4096];
    const int role = blockIdx.x >> 5;   // grid = 64
    const int grp  = blockIdx.x & 31;
    if (role == 0)
        gru_body<E_SZ, true, 0>(xh, W_ih0, W_hh0, b_ih0, b_hh0, h1, prog + grp, grp, hs);
    else
        gru_body<H_SZ, false, 1>(h1, W_ih1, W_hh1, b_ih1, b_hh1, h2, prog + grp, grp, hs);
}

__global__ __launch_bounds__(256)
void cvt_f32_f16(const float* __restrict__ in, _Float16* __restrict__ out, int n8)
{
    int i = blockIdx.x * 256 + threadIdx.x;
    if (i >= n8) return;
    const float4* p = (const float4*)in + (size_t)i * 2;
    float4 a = p[0];
    float4 b = p[1];
    half8 h;
    h[0] = (_Float16)a.x; h[1] = (_Float16)a.y; h[2] = (_Float16)a.z; h[3] = (_Float16)a.w;
    h[4] = (_Float16)b.x; h[5] = (_Float16)b.y; h[6] = (_Float16)b.z; h[7] = (_Float16)b.w;
    ((half8*)out)[i] = h;
}

__global__ __launch_bounds__(256)
void head_kernel(const float* __restrict__ h2,   // (B, H)
                 const float* __restrict__ W,    // (P, H)
                 const float* __restrict__ bias, // (P,)
                 float* __restrict__ out)        // (B, P)
{
    int idx = blockIdx.x * 256 + threadIdx.x;
    if (idx >= B_SZ * P_SZ) return;
    int b = idx / P_SZ;
    int p = idx % P_SZ;
    const float* hv = h2 + b * H_SZ;
    const float* wv = W + p * H_SZ;
    float a0 = 0.f, a1 = 0.f, a2 = 0.f, a3 = 0.f;
    #pragma unroll
    for (int i = 0; i < H_SZ; i += 4) {
        float4 h4 = *(const float4*)(hv + i);
        float4 w4 = *(const float4*)(wv + i);
        a0 += h4.x * w4.x;
        a1 += h4.y * w4.y;
        a2 += h4.z * w4.z;
        a3 += h4.w * w4.w;
    }
    out[idx] = (a0 + a1) + (a2 + a3) + bias[p];
}

extern "C" void kernel_launch(void* const* d_in, const int* in_sizes, int n_in,
                              void* d_out, int out_size, void* d_ws, size_t ws_size,
                              hipStream_t stream)
{
    const float* x      = (const float*)d_in[0];
    const float* W_ih0  = (const float*)d_in[1];
    const float* W_hh0  = (const float*)d_in[2];
    const float* b_ih0  = (const float*)d_in[3];
    const float* b_hh0  = (const float*)d_in[4];
    const float* W_ih1  = (const float*)d_in[5];
    const float* W_hh1  = (const float*)d_in[6];
    const float* b_ih1  = (const float*)d_in[7];
    const float* b_hh1  = (const float*)d_in[8];
    const float* W_head = (const float*)d_in[9];
    const float* b_head = (const float*)d_in[10];
    float* out = (float*)d_out;

    char* ws = (char*)d_ws;
    _Float16* h1  = (_Float16*)ws;                              // 64 MiB (B,T,128) fp16
    _Float16* xh  = (_Float16*)(ws + (64u << 20));              // 32 MiB (B,T,64)  fp16
    float*    h2  = (float*)   (ws + (96u << 20));              // 256 KiB (B,128)  f32
    int*      prg = (int*)     (ws + (96u << 20) + (256u << 10));

    hipMemsetAsync(prg, 0, NGRP * sizeof(int), stream);
    cvt_f32_f16<<<(B_SZ * T_SZ * E_SZ / 8 + 255) / 256, 256, 0, stream>>>(x, xh, B_SZ * T_SZ * E_SZ / 8);
    gru_fused<<<2 * NGRP, 512, 0, stream>>>(xh, h1, h2,
                                            W_ih0, W_hh0, b_ih0, b_hh0,
                                            W_ih1, W_hh1, b_ih1, b_hh1, prg);
    head_kernel<<<(B_SZ * P_SZ + 255) / 256, 256, 0, stream>>>(h2, W_head, b_head, out);
}

// Round 9
// 512.442 us; speedup vs baseline: 1.0224x; 1.0224x over previous
//
#include <hip/hip_runtime.h>

// GRU_10746008175428 round 9: r7 structure (best, 503us gru) + two cuts.
// B=512 T=512 E=64 H=128 P=96.
// 64 blocks x 512 thr: blocks 0-31 layer0 (producer), 32-63 layer1 (consumer),
// paired per 16-row batch group. Agent-scope acquire/release handoff,
// publish every 8 steps, s_sleep(8) polls. x pre-converted fp16.
// Round-9 changes vs r7:
//  - r/z hh-MFMAs C-chain into ax0/ax1 (x-part accs): -8 v_mov -8 v_add
//    per thread per step in the gate phase. Same math, reassociated.
//  - head fused into consumer epilogue: hs[0] holds h(T) in A-frag layout
//    after the last barrier; waves 0-5 MFMA vs resident fp16 W_head frags,
//    store f32 to d_out. head_kernel + h2 buffer deleted.

#define B_SZ 512
#define T_SZ 512
#define E_SZ 64
#define H_SZ 128
#define P_SZ 96
#define NB   16
#define NGRP (B_SZ / NB)          // 32
#define SC_SIG  (-1.44269504f)   // -log2(e)
#define SC_TANH (-2.88539008f)   // -2*log2(e)

typedef _Float16 half8 __attribute__((ext_vector_type(8)));
typedef float    f32x4 __attribute__((ext_vector_type(4)));

__device__ __forceinline__ float exp2_(float x) {
#if __has_builtin(__builtin_amdgcn_exp2f)
    return __builtin_amdgcn_exp2f(x);
#else
    return exp2f(x);
#endif
}
__device__ __forceinline__ float rcp_(float x) {
#if __has_builtin(__builtin_amdgcn_rcpf)
    return __builtin_amdgcn_rcpf(x);
#else
    return 1.0f / x;
#endif
}

// XOR-swizzled byte offset in a [rows][256B] LDS tile
__device__ __forceinline__ int swz256(int row, int byte) {
    return row * 256 + (byte ^ ((row & 7) << 4));
}

// One B-fragment (16 cols x 32 k) from fp32 weight matrix W, pre-scaled.
// lane: col n0+(ln&15), k = kt*32 + (ln>>4)*8 + j.
__device__ __forceinline__ void load_bfrag(const float* __restrict__ W, int ldk,
                                           int n0, int kt, int ln, float scale,
                                           half8* hi) {
    int n = n0 + (ln & 15);
    int k = kt * 32 + (ln >> 4) * 8;
    const float* p = W + (size_t)n * ldk + k;
    float4 a = *(const float4*)p;
    float4 b = *(const float4*)(p + 4);
    float v[8] = {a.x, a.y, a.z, a.w, b.x, b.y, b.z, b.w};
    half8 h;
    #pragma unroll
    for (int j = 0; j < 8; ++j)
        h[j] = (_Float16)(v[j] * scale);
    *hi = h;
}

#define LOADX(Sx, tt)                                                              \
    if ((tt) < T_SZ) {                                                             \
        _Pragma("unroll") for (int kt = 0; kt < KFX; ++kt)                         \
            Sx[kt] = *(const half8*)(xlane + (size_t)(tt) * ROWB + kt * 64);       \
    }

#define GRU_STEP(Sx, tcur, tnext)                                                  \
    {                                                                              \
        const char* hb = hs[(tcur) & 1];                                           \
        half8 ah[4];                                                               \
        _Pragma("unroll") for (int kt = 0; kt < 4; ++kt)                           \
            ah[kt] = *(const half8*)(hb + swz256(colg, kt * 64 + rgrp * 16));      \
        f32x4 ax0 = {bs0, bs0, bs0, bs0};                                          \
        f32x4 ax1 = {bs1, bs1, bs1, bs1};                                          \
        f32x4 ax2 = {bi2s, bi2s, bi2s, bi2s};                                      \
        f32x4 cNH = {bh2s, bh2s, bh2s, bh2s};                                      \
        _Pragma("unroll") for (int kt = 0; kt < KFX; ++kt) {                       \
            ax0 = __builtin_amdgcn_mfma_f32_16x16x32_f16(Sx[kt], bx[0][kt], ax0, 0, 0, 0); \
            ax1 = __builtin_amdgcn_mfma_f32_16x16x32_f16(Sx[kt], bx[1][kt], ax1, 0, 0, 0); \
            ax2 = __builtin_amdgcn_mfma_f32_16x16x32_f16(Sx[kt], bx[2][kt], ax2, 0, 0, 0); \
        }                                                                          \
        __builtin_amdgcn_s_setprio(1);                                             \
        _Pragma("unroll") for (int kt = 0; kt < 4; ++kt) {                         \
            ax0 = __builtin_amdgcn_mfma_f32_16x16x32_f16(ah[kt], bhh[0][kt], ax0, 0, 0, 0); \
            ax1 = __builtin_amdgcn_mfma_f32_16x16x32_f16(ah[kt], bhh[1][kt], ax1, 0, 0, 0); \
            cNH = __builtin_amdgcn_mfma_f32_16x16x32_f16(ah[kt], bhh[2][kt], cNH, 0, 0, 0); \
        }                                                                          \
        LOADX(Sx, tnext)                                                           \
        float hn_[4];                                                              \
        _Pragma("unroll") for (int j = 0; j < 4; ++j) {                            \
            float rr = rcp_(1.f + exp2_(ax0[j]));                                  \
            float zz = rcp_(1.f + exp2_(ax1[j]));                                  \
            float v  = ax2[j] + rr * cNH[j];                                       \
            float nn = fmaf(2.f, rcp_(1.f + exp2_(v)), -1.f);                      \
            hn_[j] = nn + zz * (hreg[j] - nn);                                     \
            hreg[j] = hn_[j];                                                      \
        }                                                                          \
        __builtin_amdgcn_s_setprio(0);                                             \
        char* hw = hs[((tcur) + 1) & 1];                                           \
        _Pragma("unroll") for (int j = 0; j < 4; ++j) {                            \
            int bb = rgrp * 4 + j;                                                 \
            *(_Float16*)(hw + swz256(bb, cw * 2)) = (_Float16)hn_[j];              \
            if constexpr (OUT_ALL) {                                               \
                ((_Float16*)hout)[((size_t)(b0 + bb) * T_SZ + (tcur)) * H_SZ + cw] \
                    = (_Float16)hn_[j];                                            \
            }                                                                      \
        }                                                                          \
        /* lgkm-only barrier: keep global loads/stores in flight across steps */   \
        asm volatile("s_waitcnt lgkmcnt(0)" ::: "memory");                         \
        __builtin_amdgcn_s_barrier();                                              \
        __builtin_amdgcn_sched_barrier(0);                                         \
    }

// ROLE 0 = producer (layer 0), ROLE 1 = consumer (layer 1 + fused head)
template<int K_IN, bool OUT_ALL, int ROLE>
__device__ __forceinline__ void gru_body(const _Float16* __restrict__ xin,
                                         const float* __restrict__ W_ih,
                                         const float* __restrict__ W_hh,
                                         const float* __restrict__ b_ih,
                                         const float* __restrict__ b_hh,
                                         void* __restrict__ hout,
                                         const float* __restrict__ W_head,
                                         const float* __restrict__ b_head,
                                         float* __restrict__ out,
                                         int* __restrict__ prog,
                                         int grp, char (*hs)[4096])
{
    constexpr int KFX  = K_IN / 32;
    constexpr int ROWB = K_IN * 2;     // fp16 row bytes

    const int tid  = threadIdx.x;
    const int ln   = tid & 63;
    const int wv   = tid >> 6;        // wave 0..7 -> col tile
    const int colg = ln & 15;
    const int rgrp = ln >> 4;
    const int b0   = grp * NB;
    const int cw   = wv * 16 + colg;  // hidden-unit column 0..127

    // ---- resident weight fragments (pre-scaled per gate) ----
    half8 bx[3][KFX];        // W_ih fp16
    half8 bhh[3][4];         // W_hh fp16
    const float gsc[3] = {SC_SIG, SC_SIG, SC_TANH};
    #pragma unroll
    for (int g = 0; g < 3; ++g) {
        int n0 = g * 128 + wv * 16;
        #pragma unroll
        for (int kt = 0; kt < KFX; ++kt)
            load_bfrag(W_ih, K_IN, n0, kt, ln, gsc[g], &bx[g][kt]);
        #pragma unroll
        for (int kt = 0; kt < 4; ++kt)
            load_bfrag(W_hh, H_SZ, n0, kt, ln, gsc[g], &bhh[g][kt]);
    }
    const float bs0  = SC_SIG  * (b_ih[cw] + b_hh[cw]);
    const float bs1  = SC_SIG  * (b_ih[128 + cw] + b_hh[128 + cw]);
    const float bi2s = SC_TANH * b_ih[256 + cw];
    const float bh2s = SC_TANH * b_hh[256 + cw];

    // consumer-only: resident head fragments (waves 0..5 cover P=96)
    half8 bph[4];
    float bhd = 0.f;
    if (ROLE == 1 && wv < 6) {
        #pragma unroll
        for (int kt = 0; kt < 4; ++kt)
            load_bfrag(W_head, H_SZ, wv * 16, kt, ln, 1.0f, &bph[kt]);
        bhd = b_head[cw];
    }

    if (tid < 256) *(float4*)(hs[0] + tid * 16) = make_float4(0.f, 0.f, 0.f, 0.f);
    float hreg[4] = {0.f, 0.f, 0.f, 0.f};

    // per-lane x row base: A-row = colg (batch), k-offset rgrp*8 elems (16B)
    const char* xlane = (const char*)xin
        + (size_t)(b0 + colg) * T_SZ * ROWB
        + rgrp * 16;

    int avail = 0;
    if (ROLE == 1) {
        while (avail < 4) {
            avail = __hip_atomic_load(prog, __ATOMIC_ACQUIRE, __HIP_MEMORY_SCOPE_AGENT);
            if (avail < 4) __builtin_amdgcn_s_sleep(8);
        }
    }

    half8 Ax[KFX], Bx2[KFX];
    LOADX(Ax, 0)
    LOADX(Bx2, 1)
    __syncthreads();

    for (int t = 0; t < T_SZ; t += 2) {
        if (ROLE == 1 && avail < T_SZ) {
            const int need = (t + 4 < T_SZ) ? t + 4 : T_SZ;
            while (avail < need) {
                avail = __hip_atomic_load(prog, __ATOMIC_ACQUIRE, __HIP_MEMORY_SCOPE_AGENT);
                if (avail < need) __builtin_amdgcn_s_sleep(8);
            }
        }
        GRU_STEP(Ax,  t,     t + 2)
        GRU_STEP(Bx2, t + 1, t + 3)
        if (ROLE == 0 && (t & 7) == 6) {
            // publish progress: own stores drained -> block barrier -> release
            asm volatile("s_waitcnt vmcnt(0)" ::: "memory");
            __builtin_amdgcn_s_barrier();
            if (tid == 0)
                __hip_atomic_store(prog, t + 2, __ATOMIC_RELEASE, __HIP_MEMORY_SCOPE_AGENT);
        }
    }

    // ---- fused head (consumer only): out = h(T) @ W_head^T + b_head ----
    // hs[0] holds h(T) in A-frag layout (T_SZ even; last barrier passed).
    if (ROLE == 1 && wv < 6) {
        half8 ahf[4];
        #pragma unroll
        for (int kt = 0; kt < 4; ++kt)
            ahf[kt] = *(const half8*)(hs[0] + swz256(colg, kt * 64 + rgrp * 16));
        f32x4 acc = {bhd, bhd, bhd, bhd};
        #pragma unroll
        for (int kt = 0; kt < 4; ++kt)
            acc = __builtin_amdgcn_mfma_f32_16x16x32_f16(ahf[kt], bph[kt], acc, 0, 0, 0);
        #pragma unroll
        for (int j = 0; j < 4; ++j)
            out[(size_t)(b0 + rgrp * 4 + j) * P_SZ + cw] = acc[j];
    }
}

__global__ __launch_bounds__(512)
void gru_fused(const _Float16* __restrict__ xh,  // (B,T,64) fp16
               _Float16* __restrict__ h1,        // (B,T,128) fp16
               const float* __restrict__ W_ih0, const float* __restrict__ W_hh0,
               const float* __restrict__ b_ih0, const float* __restrict__ b_hh0,
               const float* __restrict__ W_ih1, const float* __restrict__ W_hh1,
               const float* __restrict__ b_ih1, const float* __restrict__ b_hh1,
               const float* __restrict__ W_head, const float* __restrict__ b_head,
               float* __restrict__ out,          // (B,96) f32
               int* __restrict__ prog)
{
    __shared__ __align__(16) char hs[2][4096];
    const int role = blockIdx.x >> 5;   // grid = 64
    const int grp  = blockIdx.x & 31;
    if (role == 0)
        gru_body<E_SZ, true, 0>(xh, W_ih0, W_hh0, b_ih0, b_hh0, h1,
                                W_head, b_head, out, prog + grp, grp, hs);
    else
        gru_body<H_SZ, false, 1>(h1, W_ih1, W_hh1, b_ih1, b_hh1, nullptr,
                                 W_head, b_head, out, prog + grp, grp, hs);
}

__global__ __launch_bounds__(256)
void cvt_f32_f16(const float* __restrict__ in, _Float16* __restrict__ out, int n8)
{
    int i = blockIdx.x * 256 + threadIdx.x;
    if (i >= n8) return;
    const float4* p = (const float4*)in + (size_t)i * 2;
    float4 a = p[0];
    float4 b = p[1];
    half8 h;
    h[0] = (_Float16)a.x; h[1] = (_Float16)a.y; h[2] = (_Float16)a.z; h[3] = (_Float16)a.w;
    h[4] = (_Float16)b.x; h[5] = (_Float16)b.y; h[6] = (_Float16)b.z; h[7] = (_Float16)b.w;
    ((half8*)out)[i] = h;
}

extern "C" void kernel_launch(void* const* d_in, const int* in_sizes, int n_in,
                              void* d_out, int out_size, void* d_ws, size_t ws_size,
                              hipStream_t stream)
{
    const float* x      = (const float*)d_in[0];
    const float* W_ih0  = (const float*)d_in[1];
    const float* W_hh0  = (const float*)d_in[2];
    const float* b_ih0  = (const float*)d_in[3];
    const float* b_hh0  = (const float*)d_in[4];
    const float* W_ih1  = (const float*)d_in[5];
    const float* W_hh1  = (const float*)d_in[6];
    const float* b_ih1  = (const float*)d_in[7];
    const float* b_hh1  = (const float*)d_in[8];
    const float* W_head = (const float*)d_in[9];
    const float* b_head = (const float*)d_in[10];
    float* out = (float*)d_out;

    char* ws = (char*)d_ws;
    _Float16* h1  = (_Float16*)ws;                              // 64 MiB (B,T,128) fp16
    _Float16* xh  = (_Float16*)(ws + (64u << 20));              // 32 MiB (B,T,64)  fp16
    int*      prg = (int*)     (ws + (96u << 20));

    hipMemsetAsync(prg, 0, NGRP * sizeof(int), stream);
    cvt_f32_f16<<<(B_SZ * T_SZ * E_SZ / 8 + 255) / 256, 256, 0, stream>>>(x, xh, B_SZ * T_SZ * E_SZ / 8);
    gru_fused<<<2 * NGRP, 512, 0, stream>>>(xh, h1,
                                            W_ih0, W_hh0, b_ih0, b_hh0,
                                            W_ih1, W_hh1, b_ih1, b_hh1,
                                            W_head, b_head, out, prg);
}